// Round 2
// 817.622 us; speedup vs baseline: 1.0240x; 1.0240x over previous
//
#include <hip/hip_runtime.h>
#include <limits.h>

#define NUM_HEADS 32
#define HEAD_DIM 128
#define ROPE_DIM 64

// clang-native 4-float vector: required by __builtin_nontemporal_load/store
// (HIP's float4 is a struct and is rejected). Same 16B layout & codegen.
typedef float v4f __attribute__((ext_vector_type(4)));

// One block per token, 256 threads.
// Rope region (dims 0..63 of each head): 32 heads * 8 float4-pairs = 256 pairs,
//   one per thread. Each pair is (x1 quad at d, x2 quad at d+32); both outputs
//   computed from one load each -> every byte read exactly once.
// Pass-through region (dims 64..127): 32 heads * 16 float4 = 512 copies,
//   2 per thread, coalesced.
//
// v2 changes vs previous session's best:
//  1. Segment lookup: lane-parallel (1 load + ballot + shfl) instead of a
//     serial dependent-load scan (up to 15 chained L2 hits ~3000 cyc for
//     late-segment blocks). Cuts the per-block prologue latency ~10x.
//  2. Non-temporal loads/stores on the 512 MiB in/out streams so they do not
//     evict the L2-resident sin/cos caches (2 MB, reused by every token).
__global__ __launch_bounds__(256) void ApplyRotary_27814208209209_kernel(
    const float* __restrict__ in,
    const float* __restrict__ sin_cache,
    const float* __restrict__ cos_cache,
    const int* __restrict__ cu_seqlen,
    int n_cu,            // number of entries in cu_seqlen (== segments + 1)
    float* __restrict__ out)
{
    const int t   = blockIdx.x;
    const int tid = threadIdx.x;
    const int lane = tid & 63;

    // ---- lane-parallel segment lookup ----
    // seg = searchsorted(cu, t, side='right') - 1 = count(cu <= t) - 1
    int off;
    if (n_cu <= 64) {
        const int cuv = (lane < n_cu) ? cu_seqlen[lane] : INT_MAX;
        const unsigned long long le = __ballot(cuv <= t);   // low lanes only
        const int seg = __popcll(le) - 1;                   // >=0: cu[0]=0<=t
        off = t - __shfl(cuv, seg);
    } else {
        // fallback (never taken for this problem's 17-entry cu array)
        int seg = 0;
        while (seg + 1 < n_cu && cu_seqlen[seg + 1] <= t) seg++;
        off = t - cu_seqlen[seg];
    }

    const v4f* in4  = (const v4f*)(in  + (size_t)t * NUM_HEADS * HEAD_DIM);
    v4f*       out4 = (v4f*)      (out + (size_t)t * NUM_HEADS * HEAD_DIM);
    const v4f* sin4 = (const v4f*)(sin_cache + (size_t)off * ROPE_DIM);
    const v4f* cos4 = (const v4f*)(cos_cache + (size_t)off * ROPE_DIM);

    // ---- rope pairs ----
    {
        const int h = tid >> 3;        // head 0..31
        const int p = tid & 7;         // quad 0..7 -> dims [4p, 4p+3]
        const int base = h * (HEAD_DIM / 4);   // float4 index of head start

        const v4f a = __builtin_nontemporal_load(&in4[base + p]);      // x1
        const v4f b = __builtin_nontemporal_load(&in4[base + p + 8]);  // x2

        const v4f s1 = sin4[p];
        const v4f c1 = cos4[p];
        const v4f s2 = sin4[p + 8];
        const v4f c2 = cos4[p + 8];

        v4f oa, ob;
        // out[d]      = -x2[d]*sin[d]    + x1[d]*cos[d]        (d in [0,32))
        oa.x = fmaf(-b.x, s1.x, a.x * c1.x);
        oa.y = fmaf(-b.y, s1.y, a.y * c1.y);
        oa.z = fmaf(-b.z, s1.z, a.z * c1.z);
        oa.w = fmaf(-b.w, s1.w, a.w * c1.w);
        // out[d+32]   =  x1[d]*sin[d+32] + x2[d]*cos[d+32]
        ob.x = fmaf(a.x, s2.x, b.x * c2.x);
        ob.y = fmaf(a.y, s2.y, b.y * c2.y);
        ob.z = fmaf(a.z, s2.z, b.z * c2.z);
        ob.w = fmaf(a.w, s2.w, b.w * c2.w);

        __builtin_nontemporal_store(oa, &out4[base + p]);
        __builtin_nontemporal_store(ob, &out4[base + p + 8]);
    }

    // ---- pass-through dims 64..127 ----
    #pragma unroll
    for (int j = tid; j < NUM_HEADS * (HEAD_DIM - ROPE_DIM) / 4; j += 256) {
        const int h = j >> 4;          // 16 float4 per head in pass region
        const int q = j & 15;
        const int idx = h * (HEAD_DIM / 4) + (ROPE_DIM / 4) + q;
        const v4f v = __builtin_nontemporal_load(&in4[idx]);
        __builtin_nontemporal_store(v, &out4[idx]);
    }
}

extern "C" void kernel_launch(void* const* d_in, const int* in_sizes, int n_in,
                              void* d_out, int out_size, void* d_ws, size_t ws_size,
                              hipStream_t stream) {
    const float* in        = (const float*)d_in[0];
    const float* sin_cache = (const float*)d_in[1];
    const float* cos_cache = (const float*)d_in[2];
    const int*   cu        = (const int*)d_in[3];
    const int    n_cu      = in_sizes[3];   // 17 entries for this problem

    const int total_tokens = in_sizes[0] / (NUM_HEADS * HEAD_DIM);

    ApplyRotary_27814208209209_kernel<<<total_tokens, 256, 0, stream>>>(
        in, sin_cache, cos_cache, cu, n_cu, (float*)d_out);
}